// Round 5
// baseline (2995.852 us; speedup 1.0000x reference)
//
#include <hip/hip_runtime.h>

// Problem constants (fixed by the reference):
//   VOCAB=50000, N_NUM=5000, D=128, B=512, L=512
// Output: fp32 [262144, 128]
//
// *** R5 = MEASUREMENT ROUND, NOT AN OPTIMIZATION ***
// emb_kernel has never appeared in the rocprof top-5 (cutoff ~77-81 us =
// the harness's 512 MiB poison fills), so its true dur/FETCH/WRITE are
// unknown; 3 structural hypotheses (read-VMEM count, L3 warm, NT stores)
// all nulled at +-0.1%.  This round appends a ~70 us dependent-FMA delay
// tail after the stores to push the dispatch above the cutoff and expose
// its counters.  Traffic counters are delay-invariant; dur-70 ~= true
// kernel time.  Will be reverted next round.
//
// Kernel body is IDENTICAL to R4 (plain stores, exec-masked bias skip,
// 32-bit rows).

constexpr int D  = 128;
constexpr int BL = 512 * 512;
constexpr int POS_PER_WAVE  = 16;
constexpr int WAVES_PER_BLK = 4;   // 256 threads
constexpr int POS_PER_BLK   = POS_PER_WAVE * WAVES_PER_BLK;  // 64

constexpr int DELAY_ITERS = 42000;   // ~4 cyc/iter dep chain = ~70 us @2.4GHz

__global__ __launch_bounds__(256) void emb_kernel(
    const int*    __restrict__ feature_ids,
    const float*  __restrict__ feature_values,
    const float*  __restrict__ cat_table,
    const float*  __restrict__ num_weight,
    const float*  __restrict__ num_bias,
    float*        __restrict__ out)
{
    const int tid  = threadIdx.x;
    const int lane = tid & 63;
    const int wave = tid >> 6;
    const int wbase = blockIdx.x * POS_PER_BLK + wave * POS_PER_WAVE;  // first position

    // Wave-local routing: one coalesced load of the wave's 16 ids/values.
    const int  myp = lane & 15;
    const int  id  = feature_ids[wbase + myp];
    const float mv = feature_values[wbase + myp];
    // route < 0 -> numerical (row = -route-1); route >= 0 -> categorical row.
    const int route = (id >= 1 && id <= 5000) ? -id
                    : ((id > 5000) ? id - 5000 : 0);

    const int sub  = (lane & 31) * 4;   // float offset within the 128-wide row
    const int half = lane >> 5;         // which of the 2 positions per k-iter

    // ---- Phase 1: issue all 8 A-row loads (always needed) --------------
    float4 av[8];
    float  sc[8];
    int    brow[8];                     // bias row if numerical, else -1
#pragma unroll
    for (int k = 0; k < 8; ++k) {
        const int   p  = k * 2 + half;          // position within wave [0,16)
        const int   rt = __shfl(route, p);
        const float vv = __shfl(mv, p);
        const bool isnum = rt < 0;
        const int  row   = isnum ? (-rt - 1) : rt;
        const float* a   = (isnum ? num_weight : cat_table) + row * D + sub;
        av[k]   = *(const float4*)a;
        sc[k]   = isnum ? vv : 1.0f;
        brow[k] = isnum ? row : -1;
    }

    // ---- Phase 2: B-row loads only where numerical ----------------------
    float4 bv[8];
#pragma unroll
    for (int k = 0; k < 8; ++k) {
        bv[k] = make_float4(0.f, 0.f, 0.f, 0.f);
        if (brow[k] >= 0)
            bv[k] = *(const float4*)(num_bias + brow[k] * D + sub);
    }

    // ---- Phase 3: fma + plain coalesced store ---------------------------
    float* const obase = out + (long long)wbase * D;
#pragma unroll
    for (int k = 0; k < 8; ++k) {
        float4 r;
        r.x = fmaf(av[k].x, sc[k], bv[k].x);
        r.y = fmaf(av[k].y, sc[k], bv[k].y);
        r.z = fmaf(av[k].z, sc[k], bv[k].z);
        r.w = fmaf(av[k].w, sc[k], bv[k].w);
        *(float4*)(obase + (k * 64 + lane) * 4) = r;
    }

    // ---- Phase 4 (R5 only): ~70 us serial-FMA delay tail ---------------
    // Dependent chain, 4 cyc/iter; every wave spins after its real work so
    // dispatch dur ~= true_dur + 70 us.  Pushes emb_kernel above the
    // top-5 cutoff to expose FETCH_SIZE / WRITE_SIZE.  REVERT NEXT ROUND.
    {
        float x = sc[0] + av[7].x;
#pragma clang loop unroll(disable)
        for (int i = 0; i < DELAY_ITERS; ++i)
            x = fmaf(x, 1.0000001f, 1e-30f);
        asm volatile("" :: "v"(x));   // keep chain live, no store
    }
}

extern "C" void kernel_launch(void* const* d_in, const int* in_sizes, int n_in,
                              void* d_out, int out_size, void* d_ws, size_t ws_size,
                              hipStream_t stream) {
    const int*   feature_ids    = (const int*)  d_in[0];
    const float* feature_values = (const float*)d_in[1];
    const float* cat_table      = (const float*)d_in[2];
    const float* num_weight     = (const float*)d_in[3];
    const float* num_bias       = (const float*)d_in[4];
    float*       out            = (float*)      d_out;

    const int blocks = BL / POS_PER_BLK;   // 4096, exact
    emb_kernel<<<blocks, 256, 0, stream>>>(
        feature_ids, feature_values, cat_table, num_weight, num_bias, out);
}

// Round 6
// 211.170 us; speedup vs baseline: 14.1869x; 14.1869x over previous
//
#include <hip/hip_runtime.h>

// Problem constants (fixed by the reference):
//   VOCAB=50000, N_NUM=5000, D=128, B=512, L=512
// Output: fp32 [262144, 128]
//
// R6: ordered two-phase execution.
// R5's measurement: emb_kernel itself is ~157 us of the 179 us span
// (R5_total - R4_total subtraction), moving 202 MB (FETCH 68 + WRITE 134)
// = 1.3 TB/s effective vs ~32 us traffic floor.  Issue count (R1), cache
// warmth (R3, unordered) and store path (R4) are nulled; occupancy/MLP
// are ample.  Surviving theory: random 512B gather reads interleaved
// device-wide with the 134 MB write stream tank DRAM efficiency.
// Fix: Phase 1 = all 1024 co-resident blocks stream-read the tables
// (30 MB sequential burst -> L2/L3 warm), grid barrier, Phase 2 =
// gathers hit warm cache, HBM sees a near-pure write stream.
// Barrier is poison-immune (module-scope counter, target = next multiple
// of gridDim, monotone across graph replays) and timeout-bounded (a
// failed barrier degrades to unordered perf, never a hang).

constexpr int D  = 128;
constexpr int BL = 512 * 512;                 // 262144 positions
constexpr int BLOCKS   = 1024;                // co-resident: 4 blocks/CU x 256 CU
constexpr int THREADS  = 256;                 // 4 waves
constexpr int POS_PER_BLOCK = BL / BLOCKS;    // 256
constexpr int POS_PER_WAVE  = POS_PER_BLOCK / 4;  // 64
constexpr int GRID_THREADS  = BLOCKS * THREADS;   // 262144

constexpr int CAT_F4 = 45001 * (D / 4);       // 1,440,032 float4
constexpr int NUM_F4 = 5000  * (D / 4);       //   160,000 float4

__device__ unsigned g_arrive = 0;             // persists across graph replays

__global__ __launch_bounds__(256, 4) void emb_kernel(
    const int*    __restrict__ feature_ids,
    const float*  __restrict__ feature_values,
    const float*  __restrict__ cat_table,
    const float*  __restrict__ num_weight,
    const float*  __restrict__ num_bias,
    float*        __restrict__ out)
{
    const int tid  = threadIdx.x;
    const int lane = tid & 63;
    const int wave = tid >> 6;
    const int gtid = blockIdx.x * THREADS + tid;

    // ---- Phase 0: preload this wave's 64 ids/values (lane p owns pos p) --
    const int wpos0 = blockIdx.x * POS_PER_BLOCK + wave * POS_PER_WAVE;
    const int   id = feature_ids[wpos0 + lane];
    const float mv = feature_values[wpos0 + lane];
    // route < 0 -> numerical (row = -route-1); route >= 0 -> categorical row.
    const int route = (id >= 1 && id <= 5000) ? -id
                    : ((id > 5000) ? id - 5000 : 0);

    // ---- Phase 1: sequential streaming warm of all three tables ---------
    // Pure-read burst at stream efficiency; populates L2/L3 so Phase 2
    // gathers never touch HBM.  Loads kept live via empty asm.
    {
        float acc = 0.0f;
        const float4* ct = (const float4*)cat_table;
#pragma unroll
        for (int i = 0; i < 6; ++i) {
            const int j = gtid + i * GRID_THREADS;
            if (j < CAT_F4) { float4 w = ct[j]; acc += w.x + w.w; }
        }
        if (gtid < NUM_F4) {
            float4 w = ((const float4*)num_weight)[gtid];
            float4 b = ((const float4*)num_bias)[gtid];
            acc += w.x + w.w + b.x + b.w;
        }
        asm volatile("" :: "v"(acc));   // keep loads live (forces waitcnt)
    }

    // ---- Grid barrier (poison-immune, timeout-bounded) -------------------
    // Each launch adds exactly BLOCKS to g_arrive; blocks of launch n spin
    // until g_arrive reaches the next multiple of BLOCKS.  Co-residency is
    // guaranteed by __launch_bounds__(256,4) with grid = 4 x 256 CUs.
    __syncthreads();
    if (tid == 0) {
        const unsigned old    = atomicAdd(&g_arrive, 1u);       // device scope
        const unsigned target = ((old >> 10) + 1u) << 10;       // next x1024
        int spins = 0;
        while (__hip_atomic_load(&g_arrive, __ATOMIC_RELAXED,
                                 __HIP_MEMORY_SCOPE_AGENT) < target
               && spins < 65536) {
            ++spins;
            __builtin_amdgcn_s_sleep(2);
        }
    }
    __syncthreads();

    // ---- Phase 2: gather (cache-hot) + fma + pure write stream ----------
    const int sub  = (lane & 31) * 4;   // float offset within the 128-wide row
    const int half = lane >> 5;

    for (int m = 0; m < 4; ++m) {       // 4 chunks of 16 positions per wave
        float4 av[8];
        float  sc[8];
        int    brow[8];
#pragma unroll
        for (int k = 0; k < 8; ++k) {
            const int   p  = m * 16 + k * 2 + half;   // position in wave [0,64)
            const int   rt = __shfl(route, p);
            const float vv = __shfl(mv, p);
            const bool isnum = rt < 0;
            const int  row   = isnum ? (-rt - 1) : rt;
            const float* a   = (isnum ? num_weight : cat_table) + row * D + sub;
            av[k]   = *(const float4*)a;
            sc[k]   = isnum ? vv : 1.0f;
            brow[k] = isnum ? row : -1;
        }

        float4 bv[8];
#pragma unroll
        for (int k = 0; k < 8; ++k) {
            bv[k] = make_float4(0.f, 0.f, 0.f, 0.f);
            if (brow[k] >= 0)
                bv[k] = *(const float4*)(num_bias + brow[k] * D + sub);
        }

        float* const obase = out + (long long)(wpos0 + m * 16) * D;
#pragma unroll
        for (int k = 0; k < 8; ++k) {
            float4 r;
            r.x = fmaf(av[k].x, sc[k], bv[k].x);
            r.y = fmaf(av[k].y, sc[k], bv[k].y);
            r.z = fmaf(av[k].z, sc[k], bv[k].z);
            r.w = fmaf(av[k].w, sc[k], bv[k].w);
            *(float4*)(obase + (k * 64 + lane) * 4) = r;
        }
    }
}

extern "C" void kernel_launch(void* const* d_in, const int* in_sizes, int n_in,
                              void* d_out, int out_size, void* d_ws, size_t ws_size,
                              hipStream_t stream) {
    const int*   feature_ids    = (const int*)  d_in[0];
    const float* feature_values = (const float*)d_in[1];
    const float* cat_table      = (const float*)d_in[2];
    const float* num_weight     = (const float*)d_in[3];
    const float* num_bias       = (const float*)d_in[4];
    float*       out            = (float*)      d_out;

    emb_kernel<<<BLOCKS, THREADS, 0, stream>>>(
        feature_ids, feature_values, cat_table, num_weight, num_bias, out);
}

// Round 7
// 178.413 us; speedup vs baseline: 16.7917x; 1.1836x over previous
//
#include <hip/hip_runtime.h>

// Problem constants (fixed by the reference):
//   VOCAB=50000, N_NUM=5000, D=128, B=512, L=512
// Output: fp32 [262144, 128]
//
// R7 = REVERT to R4 (session best, 179.18 us).
// Evidence ledger: R1 (-45% read VMEM) null; R3 (unordered L3 warm) null;
// R4 (NT->plain stores) -2.9 us; R5 (delay probe) measured kernel=157 us,
// FETCH 68 MB / WRITE 134 MB; R6 (grid-barrier phase separation) kernel
// alone 93 us but total 211 us — the harness's ~671 MB poison fills
// normally OVERLAP the kernel (R4 span = 873 MB @ 5.6 TB/s aggregate =
// mixed-stream DRAM ceiling); the barrier serialized them.  The span is
// system-bytes-bound: fills (harness-fixed) + compulsory kernel traffic
// at the mixed ceiling.  All kernel-side levers are null or
// overlap-negative => this structure is the practical roofline.

constexpr int D  = 128;
constexpr int BL = 512 * 512;
constexpr int POS_PER_WAVE  = 16;
constexpr int WAVES_PER_BLK = 4;   // 256 threads
constexpr int POS_PER_BLK   = POS_PER_WAVE * WAVES_PER_BLK;  // 64

__global__ __launch_bounds__(256) void emb_kernel(
    const int*    __restrict__ feature_ids,
    const float*  __restrict__ feature_values,
    const float*  __restrict__ cat_table,
    const float*  __restrict__ num_weight,
    const float*  __restrict__ num_bias,
    float*        __restrict__ out)
{
    const int tid  = threadIdx.x;
    const int lane = tid & 63;
    const int wave = tid >> 6;
    const int wbase = blockIdx.x * POS_PER_BLK + wave * POS_PER_WAVE;  // first position

    // Wave-local routing: one coalesced load of the wave's 16 ids/values
    // (lanes 16.. replicate — same cache lines, broadcast in the TA).
    const int  myp = lane & 15;
    const int  id  = feature_ids[wbase + myp];
    const float mv = feature_values[wbase + myp];
    // route < 0  -> numerical, row = -route-1
    // route >= 0 -> categorical row (0 for padding id 0)
    const int route = (id >= 1 && id <= 5000) ? -id
                    : ((id > 5000) ? id - 5000 : 0);

    const int sub  = (lane & 31) * 4;   // float offset within the 128-wide row
    const int half = lane >> 5;         // which of the 2 positions per k-iter

    // ---- Phase 1: issue all 8 A-row loads (always needed) --------------
    float4 av[8];
    float  sc[8];
    int    brow[8];                     // bias row if numerical, else -1
#pragma unroll
    for (int k = 0; k < 8; ++k) {
        const int   p  = k * 2 + half;          // position within wave [0,16)
        const int   rt = __shfl(route, p);
        const float vv = __shfl(mv, p);
        const bool isnum = rt < 0;
        const int  row   = isnum ? (-rt - 1) : rt;     // 32-bit, fits easily
        const float* a   = (isnum ? num_weight : cat_table) + row * D + sub;
        av[k]   = *(const float4*)a;
        sc[k]   = isnum ? vv : 1.0f;
        brow[k] = isnum ? row : -1;
    }

    // ---- Phase 2: B-row loads only where numerical ----------------------
    // isnum is uniform per 32-lane half => exec-masked branch; fully
    // skipped (s_cbranch_execz) when both halves are categorical (~81%).
    float4 bv[8];
#pragma unroll
    for (int k = 0; k < 8; ++k) {
        bv[k] = make_float4(0.f, 0.f, 0.f, 0.f);
        if (brow[k] >= 0)
            bv[k] = *(const float4*)(num_bias + brow[k] * D + sub);
    }

    // ---- Phase 3: fma + plain coalesced store ---------------------------
    // categorical: fma(av, 1.0, 0) == av ; numerical: av*v + bias.
    float* const obase = out + (long long)wbase * D;
#pragma unroll
    for (int k = 0; k < 8; ++k) {
        float4 r;
        r.x = fmaf(av[k].x, sc[k], bv[k].x);
        r.y = fmaf(av[k].y, sc[k], bv[k].y);
        r.z = fmaf(av[k].z, sc[k], bv[k].z);
        r.w = fmaf(av[k].w, sc[k], bv[k].w);
        // segment index within wave region: k*64 + lane (contiguous 1 KB/iter)
        *(float4*)(obase + (k * 64 + lane) * 4) = r;
    }
}

extern "C" void kernel_launch(void* const* d_in, const int* in_sizes, int n_in,
                              void* d_out, int out_size, void* d_ws, size_t ws_size,
                              hipStream_t stream) {
    const int*   feature_ids    = (const int*)  d_in[0];
    const float* feature_values = (const float*)d_in[1];
    const float* cat_table      = (const float*)d_in[2];
    const float* num_weight     = (const float*)d_in[3];
    const float* num_bias       = (const float*)d_in[4];
    float*       out            = (float*)      d_out;

    const int blocks = BL / POS_PER_BLK;   // 4096, exact
    emb_kernel<<<blocks, 256, 0, stream>>>(
        feature_ids, feature_values, cat_table, num_weight, num_bias, out);
}